// Round 4
// baseline (37.228 us; speedup 1.0000x reference)
//
#include <hip/hip_runtime.h>
#include <math.h>

constexpr int Bn = 64, Sn = 6, Tn = 2000, Cn = 25;
constexpr int COLS = Sn * Tn;              // 12000
constexpr int ROWS = Bn * Sn * Tn;         // 768000
constexpr int BDIM = 64;                   // 1 wave per block: no barriers anywhere

// ---- fret geometry: 256-row tiles, async-staged, double-buffered ----
constexpr int TROWS = 256;                 // rows per tile
constexpr int TF4   = TROWS * Cn / 4;      // 1600 float4 per tile
constexpr int NCALL = TF4 / 64;            // 25 coalesced global_load_lds per tile
constexpr int TPB   = 4;                   // tiles per block
constexpr int NTILE = ROWS / TROWS;        // 3000
constexpr int FBLK  = NTILE / TPB;         // 750 fret blocks (exact)
constexpr int FPAD  = 768;

// ---- onset geometry ----
constexpr int CPT  = 4;                    // cols per thread (float4)
constexpr int CQN  = COLS / CPT;           // 3000 col-quads
constexpr int OBLK = (CQN + BDIM - 1) / BDIM;   // 47 onset blocks
constexpr int OPAD = 64;
constexpr int GRID = OBLK + FBLK;          // 797

typedef const __attribute__((address_space(1))) unsigned int guint;
typedef __attribute__((address_space(3)))       unsigned int luint;

static __device__ __forceinline__ float comp(const float4& v, int j) {
    return j == 0 ? v.x : j == 1 ? v.y : j == 2 ? v.z : v.w;  // j is unroll-constant
}

// Segmented (<=2 contiguous strings per wave) butterfly reduce + LDS add.
static __device__ __forceinline__ void seg_reduce_add(float* ls, int s, float v, int lane) {
    const int s0 = __shfl(s, 0, 64);
    const int s1 = __shfl(s, 63, 64);
    if (s0 == s1) {                         // wave-uniform branch
        float a = v;
        #pragma unroll
        for (int off = 32; off; off >>= 1) a += __shfl_xor(a, off, 64);
        if (lane == 0) atomicAdd(&ls[s0], a);
    } else {
        float a = (s == s0) ? v : 0.0f;
        float b = (s == s0) ? 0.0f : v;
        #pragma unroll
        for (int off = 32; off; off >>= 1) {
            a += __shfl_xor(a, off, 64);
            b += __shfl_xor(b, off, 64);
        }
        if (lane == 0) { atomicAdd(&ls[s0], a); atomicAdd(&ls[s1], b); }
    }
}

__global__ __launch_bounds__(BDIM) void main_kernel(const float4* __restrict__ x4,
                                                    const int4*   __restrict__ tgt4,
                                                    const float*  __restrict__ ox,
                                                    const float*  __restrict__ ot,
                                                    float* __restrict__ pf,
                                                    float* __restrict__ po) {
    __shared__ float buf[2][TROWS * Cn];   // 2 x 25.6 KB tile double-buffer
    __shared__ int   tbuf[2][TROWS];       // 2 x 1 KB target double-buffer
    __shared__ float ws[Sn];
    const int lane = threadIdx.x;          // block = exactly one wave
    if (lane < Sn) ws[lane] = 0.0f;        // same-wave LDS order: no barrier needed

    if (blockIdx.x < OBLK) {
        // -------- onset path: softmax over B, 4 consecutive columns per thread --------
        const int cq = blockIdx.x * BDIM + lane;
        float on = 0.0f;
        int   s  = Sn - 1;                  // tail lanes: contiguity-safe string
        if (cq < CQN) {
            s = (cq * CPT) / Tn;            // quad never crosses string (2000 % 4 == 0)
            const float4* oxp = (const float4*)ox + cq;
            const float4* otp = (const float4*)ot + cq;
            float M[4], S_[4], ts[4], txs[4];
            #pragma unroll
            for (int j = 0; j < 4; ++j) { M[j] = -INFINITY; S_[j] = 0.0f; ts[j] = 0.0f; txs[j] = 0.0f; }
            for (int b0 = 0; b0 < Bn; b0 += 8) {
                float4 xv[8], tv[8];
                #pragma unroll
                for (int k = 0; k < 8; ++k) xv[k] = oxp[(long)(b0 + k) * (COLS / 4)];
                #pragma unroll
                for (int k = 0; k < 8; ++k) tv[k] = otp[(long)(b0 + k) * (COLS / 4)];
                #pragma unroll
                for (int j = 0; j < 4; ++j) {
                    float cm = -INFINITY;
                    #pragma unroll
                    for (int k = 0; k < 8; ++k) cm = fmaxf(cm, comp(xv[k], j));
                    float cs = 0.0f;
                    #pragma unroll
                    for (int k = 0; k < 8; ++k) cs += __expf(comp(xv[k], j) - cm);
                    const float nm = fmaxf(M[j], cm);
                    S_[j] = S_[j] * __expf(M[j] - nm) + cs * __expf(cm - nm);  // exp(-inf)=0 first iter
                    M[j]  = nm;
                    #pragma unroll
                    for (int k = 0; k < 8; ++k) {
                        const float t = comp(tv[k], j);
                        ts[j]  += t;
                        txs[j] += t * comp(xv[k], j);
                    }
                }
            }
            #pragma unroll
            for (int j = 0; j < 4; ++j) on += ts[j] * (M[j] + __logf(S_[j])) - txs[j];
        }
        seg_reduce_add(ws, s, on, lane);
        if (lane < Sn) po[lane * OPAD + blockIdx.x] = ws[lane];   // in-order LDS: safe
    } else {
        // -------- fret path: async coalesced staging + per-lane CE over 25 classes ----
        const int fb    = blockIdx.x - OBLK;
        const int tile0 = fb * TPB;

        // stage(t): 25 coalesced 1KB global_load_lds + 1 for 256 targets.
        // LDS dest = wave-uniform base + lane*16 (HW rule); global src per-lane.
        auto stage = [&](int t) {
            const int b = t & 1;
            const float4* gs = x4 + (long)(tile0 + t) * TF4 + lane;
            #pragma unroll
            for (int k = 0; k < NCALL; ++k)
                __builtin_amdgcn_global_load_lds((guint*)(gs + k * 64),
                                                 (luint*)&buf[b][k * 256], 16, 0, 0);
            __builtin_amdgcn_global_load_lds((guint*)(tgt4 + (long)(tile0 + t) * (TROWS / 4) + lane),
                                             (luint*)&tbuf[b][0], 16, 0, 0);
        };

        auto compute = [&](int t) {
            const int b     = t & 1;
            const int gbase = (tile0 + t) * TROWS;
            #pragma unroll
            for (int j = 0; j < 4; ++j) {
                const int rl = 64 * j + lane;
                const float* rp = &buf[b][rl * Cn];   // stride-25 dwords: conflict-free
                const int tc = tbuf[b][rl];
                float m = -INFINITY, xt = 0.0f;
                #pragma unroll
                for (int c = 0; c < Cn; ++c) {
                    const float e = rp[c];
                    m  = fmaxf(m, e);
                    xt = (c == tc) ? e : xt;          // select, no runtime reg index
                }
                float ss = 0.0f;
                #pragma unroll
                for (int c = 0; c < Cn; ++c) ss += __expf(rp[c] - m);
                const float nll = m + __logf(ss) - xt;
                const int s = ((gbase + rl) / Tn) % Sn;   // 64 consecutive rows: <=2 strings
                seg_reduce_add(ws, s, nll, lane);
            }
        };

        stage(0);
        #pragma unroll
        for (int t = 0; t < TPB; ++t) {
            if (t + 1 < TPB) {
                stage(t + 1);                          // prefetch next tile (26 loads in flight)
                asm volatile("s_waitcnt vmcnt(26)" ::: "memory");  // tile t complete; t+1 still flying
            } else {
                asm volatile("s_waitcnt vmcnt(0)" ::: "memory");   // final tile drain
            }
            compute(t);
        }
        if (lane < Sn) pf[lane * FPAD + fb] = ws[lane];
    }
}

__global__ __launch_bounds__(1024) void finish_kernel(const float* __restrict__ pf,
                                                      const float* __restrict__ po,
                                                      float* __restrict__ out) {
    __shared__ float acc[2 * Sn];
    const int tid  = threadIdx.x;
    const int lane = tid & 63;
    if (tid < 2 * Sn) acc[tid] = 0.0f;
    __syncthreads();

    // ---- fret partials: 6 independent coalesced sweeps (750 < 1024: one load each) ----
    float fs[Sn];
    #pragma unroll
    for (int s = 0; s < Sn; ++s) {
        float v = 0.0f;
        for (int i = tid; i < FBLK; i += 1024) v += pf[s * FPAD + i];
        fs[s] = v;
    }
    #pragma unroll
    for (int off = 32; off; off >>= 1) {
        #pragma unroll
        for (int s = 0; s < Sn; ++s) fs[s] += __shfl_xor(fs[s], off, 64);
    }
    if (lane == 0) {
        #pragma unroll
        for (int s = 0; s < Sn; ++s) atomicAdd(&acc[s], fs[s]);
    }

    // ---- onset partials: wave w sums string w (47 entries) ----
    const int wv = tid >> 6;
    if (wv < Sn) {
        float v = (lane < OBLK) ? po[wv * OPAD + lane] : 0.0f;
        #pragma unroll
        for (int off = 32; off; off >>= 1) v += __shfl_xor(v, off, 64);
        if (lane == 0) acc[Sn + wv] = v;
    }
    __syncthreads();

    if (tid == 0) {
        float fret = 0.0f, on = 0.0f, fsv[Sn], osv[Sn];
        #pragma unroll
        for (int s = 0; s < Sn; ++s) {
            fsv[s] = acc[s] * (1.0f / Bn);              // mean over batch
            osv[s] = acc[Sn + s];
            fret += fsv[s];
            on   += osv[s];
        }
        out[0] = 0.5f * fret + 0.5f * on;               // WEIGHT_FRET_ONSET = 0.5
        out[1] = fret;
        out[2] = on;
        #pragma unroll
        for (int s = 0; s < Sn; ++s) { out[3 + s] = fsv[s]; out[9 + s] = osv[s]; }
    }
}

extern "C" void kernel_launch(void* const* d_in, const int* in_sizes, int n_in,
                              void* d_out, int out_size, void* d_ws, size_t ws_size,
                              hipStream_t stream) {
    const float* output_fret  = (const float*)d_in[0];
    const int*   target_fret  = (const int*)d_in[1];
    const float* output_onset = (const float*)d_in[2];
    const float* target_onset = (const float*)d_in[3];
    float* pf  = (float*)d_ws;                 // [Sn][FPAD]
    float* po  = pf + Sn * FPAD;               // [Sn][OPAD]
    float* out = (float*)d_out;

    main_kernel<<<GRID, BDIM, 0, stream>>>((const float4*)output_fret,
                                           (const int4*)target_fret,
                                           output_onset, target_onset, pf, po);
    finish_kernel<<<1, 1024, 0, stream>>>(pf, po, out);
}